// Round 1
// baseline (156.986 us; speedup 1.0000x reference)
//
#include <hip/hip_runtime.h>

#define B      8192
#define C      2048
#define HALF   4096
#define L      6
#define NRGB   4
#define BT     (B + L)                    // 8198
#define XOUT_ELEMS ((size_t)BT * C)       // 16789504
#define GROUPS 64
#define RPG    (B / GROUPS)               // 128 rows per group

// ---------------- Kernel 1: per-row attention score + copy x -> x_out ----------------
// score[b] = dot(x[b], att_w[cams[b]]) + att_b[cams[b]]
__global__ __launch_bounds__(256) void k_score_copy(
    const float* __restrict__ x, const int* __restrict__ cams,
    const float* __restrict__ att_w, const float* __restrict__ att_b,
    float* __restrict__ xout, float* __restrict__ scores) {
  const int b   = blockIdx.x;
  const int tid = threadIdx.x;
  const int cam = cams[b];                               // uniform across block
  const float4* __restrict__ xr = (const float4*)(x     + (size_t)b   * C);
  const float4* __restrict__ wr = (const float4*)(att_w + (size_t)cam * C);
  float4* __restrict__ orow     = (float4*)(xout + (size_t)b * C);

  // C/4 = 512 float4 per row, 2 per thread
  float4 x0 = xr[tid];
  float4 x1 = xr[tid + 256];
  float4 w0 = wr[tid];
  float4 w1 = wr[tid + 256];
  orow[tid]       = x0;
  orow[tid + 256] = x1;

  float acc = x0.x*w0.x + x0.y*w0.y + x0.z*w0.z + x0.w*w0.w
            + x1.x*w1.x + x1.y*w1.y + x1.z*w1.z + x1.w*w1.w;
  #pragma unroll
  for (int off = 32; off > 0; off >>= 1) acc += __shfl_down(acc, off, 64);

  __shared__ float ls[4];
  if ((tid & 63) == 0) ls[tid >> 6] = acc;
  __syncthreads();
  if (tid == 0)
    scores[b] = ls[0] + ls[1] + ls[2] + ls[3] + att_b[cam];
}

// ---------------- Kernel 2: per-cam denom + counts + cam-node degree factors ----------------
// stats layout: [0..5]=denom, [6..11]=counts, [12..17]=Dc (cam-node rsqrt degree)
__global__ __launch_bounds__(256) void k_stats(
    const float* __restrict__ scores, const int* __restrict__ cams,
    float* __restrict__ stats) {
  const int tid = threadIdx.x;
  float d0=0,d1=0,d2=0,d3=0,d4=0,d5=0;
  float n0=0,n1=0,n2=0,n3=0,n4=0,n5=0;
  for (int b = tid; b < B; b += 256) {
    const int   c = cams[b];
    const float s = scores[b];
    if      (c == 0) { d0 += s; n0 += 1.f; }
    else if (c == 1) { d1 += s; n1 += 1.f; }
    else if (c == 2) { d2 += s; n2 += 1.f; }
    else if (c == 3) { d3 += s; n3 += 1.f; }
    else if (c == 4) { d4 += s; n4 += 1.f; }
    else             { d5 += s; n5 += 1.f; }
  }
  __shared__ float sd[12][256];           // 12 KB
  sd[0][tid]=d0; sd[1][tid]=d1; sd[2][tid]=d2; sd[3][tid]=d3; sd[4][tid]=d4; sd[5][tid]=d5;
  sd[6][tid]=n0; sd[7][tid]=n1; sd[8][tid]=n2; sd[9][tid]=n3; sd[10][tid]=n4; sd[11][tid]=n5;
  __syncthreads();
  for (int off = 128; off > 0; off >>= 1) {
    if (tid < off) {
      #pragma unroll
      for (int l = 0; l < 12; ++l) sd[l][tid] += sd[l][tid + off];
    }
    __syncthreads();
  }
  if (tid < 12) stats[tid] = sd[tid][0];
  if (tid == 0) {
    const float nr = sd[6][0] + sd[7][0] + sd[8][0] + sd[9][0];   // #RGB samples
    const float ni = sd[10][0] + sd[11][0];                        // #IR samples
    #pragma unroll
    for (int l = 0; l < L; ++l)
      stats[12 + l] = rsqrtf(((l < NRGB) ? ni : nr) + 1.0f);       // cam-node degree
  }
}

// ---------------- Kernel 3: grouped partial per-cam weighted column sums ----------------
// partials[g][l][c] = sum over rows r in group g with cams[r]==l of x[r][c]*score[r]
__global__ __launch_bounds__(256) void k_partials(
    const float* __restrict__ x, const int* __restrict__ cams,
    const float* __restrict__ scores, float* __restrict__ partials) {
  const int col4 = blockIdx.x * 256 + threadIdx.x;     // [0, 512)
  const int g    = blockIdx.y;
  const int r0   = g * RPG;
  const float4* __restrict__ x4 = (const float4*)x;
  float4 a0={0,0,0,0}, a1={0,0,0,0}, a2={0,0,0,0}, a3={0,0,0,0}, a4={0,0,0,0}, a5={0,0,0,0};
  for (int r = r0; r < r0 + RPG; ++r) {
    const int   c = cams[r];                            // uniform across block
    const float s = scores[r];
    float4 xv = x4[(size_t)r * (C/4) + col4];
    float4 v; v.x = xv.x*s; v.y = xv.y*s; v.z = xv.z*s; v.w = xv.w*s;
    if      (c == 0) { a0.x+=v.x; a0.y+=v.y; a0.z+=v.z; a0.w+=v.w; }
    else if (c == 1) { a1.x+=v.x; a1.y+=v.y; a1.z+=v.z; a1.w+=v.w; }
    else if (c == 2) { a2.x+=v.x; a2.y+=v.y; a2.z+=v.z; a2.w+=v.w; }
    else if (c == 3) { a3.x+=v.x; a3.y+=v.y; a3.z+=v.z; a3.w+=v.w; }
    else if (c == 4) { a4.x+=v.x; a4.y+=v.y; a4.z+=v.z; a4.w+=v.w; }
    else             { a5.x+=v.x; a5.y+=v.y; a5.z+=v.z; a5.w+=v.w; }
  }
  float4* __restrict__ p4 = (float4*)partials;
  const size_t base = ((size_t)g * L) * (C/4) + col4;
  p4[base + 0*(C/4)] = a0;
  p4[base + 1*(C/4)] = a1;
  p4[base + 2*(C/4)] = a2;
  p4[base + 3*(C/4)] = a3;
  p4[base + 4*(C/4)] = a4;
  p4[base + 5*(C/4)] = a5;
}

// ---------------- Kernel 4: reduce partials -> tail rows of x_out ----------------
__global__ __launch_bounds__(256) void k_tail(
    const float* __restrict__ partials, const float* __restrict__ stats,
    const float* __restrict__ running_mean, float* __restrict__ xout) {
  const int l    = blockIdx.y;                          // [0, 6)
  const int col4 = blockIdx.x * 256 + threadIdx.x;      // [0, 512)
  const float4* __restrict__ p4 = (const float4*)partials;
  float4 s = {0,0,0,0};
  for (int g = 0; g < GROUPS; ++g) {
    float4 v = p4[((size_t)g * L + l) * (C/4) + col4];
    s.x += v.x; s.y += v.y; s.z += v.z; s.w += v.w;
  }
  const float denom = stats[l];
  const float cnt   = stats[6 + l];
  const float4 rm   = ((const float4*)running_mean)[(size_t)l * (C/4) + col4];
  const float inv   = 1.0f / denom;
  float4 o;
  if (cnt > 0.0f) { o.x = s.x*inv; o.y = s.y*inv; o.z = s.z*inv; o.w = s.w*inv; }
  else            { o = rm; }
  ((float4*)xout)[((size_t)B + l) * (C/4) + col4] = o;
}

// ---------------- Kernel 5: write adjacency ----------------
// adj[i][j] = D[i] * graph[i][j] * D[j]; graph symmetric.
// Sample-row degree: 4096 + (cam<NRGB ? 2 : 4)  -> two possible D_s values.
// Cam-node degree: (#samples of other modality) + 1 -> stats[12+l].
__global__ __launch_bounds__(256) void k_adj(
    const int* __restrict__ cams, const float* __restrict__ stats,
    float* __restrict__ adj) {
  const int i   = blockIdx.x;
  const int tid = threadIdx.x;
  const float ds_rgb = rsqrtf((float)HALF + 2.0f);   // 1/sqrt(4098)
  const float ds_ir  = rsqrtf((float)HALF + 4.0f);   // 1/sqrt(4100)
  float2* __restrict__ row = (float2*)(adj + (size_t)i * BT);   // row stride 8198 floats, 8B-aligned
  const int2* __restrict__ cams2 = (const int2*)cams;

  if (i < B) {
    const int  ci     = cams[i];
    const float Di    = (ci < NRGB) ? ds_rgb : ds_ir;
    const bool half_i = (i < HALF);
    for (int k = tid; k < HALF; k += 256) {           // j = 2k, 2k+1 in [0, 8192)
      const bool same = ((k < HALF/2) == half_i);     // both j's in same half as each other
      const int2 c = cams2[k];
      float2 v;
      v.x = same ? Di * ((c.x < NRGB) ? ds_rgb : ds_ir) : 0.0f;
      v.y = same ? Di * ((c.y < NRGB) ? ds_rgb : ds_ir) : 0.0f;
      row[k] = v;
    }
    if (tid < 3) {                                     // cam columns j in [8192, 8198)
      const int k  = HALF + tid;
      const int l0 = 2 * tid;
      const bool rgb_i = (ci < NRGB);
      float2 v;
      v.x = (rgb_i != (l0     < NRGB)) ? Di * stats[12 + l0]     : 0.0f;
      v.y = (rgb_i != ((l0+1) < NRGB)) ? Di * stats[12 + l0 + 1] : 0.0f;
      row[k] = v;
    }
  } else {
    const int   l     = i - B;
    const float Dcl   = stats[12 + l];
    const bool  rgb_l = (l < NRGB);
    for (int k = tid; k < HALF; k += 256) {
      const int2 c = cams2[k];
      float2 v;
      v.x = ((c.x < NRGB) != rgb_l) ? Dcl * ((c.x < NRGB) ? ds_rgb : ds_ir) : 0.0f;
      v.y = ((c.y < NRGB) != rgb_l) ? Dcl * ((c.y < NRGB) ? ds_rgb : ds_ir) : 0.0f;
      row[k] = v;
    }
    if (tid < 3) {
      const int k  = HALF + tid;
      const int l0 = 2 * tid;
      float2 v;
      v.x = (l0     == l) ? Dcl * Dcl : 0.0f;
      v.y = (l0 + 1 == l) ? Dcl * Dcl : 0.0f;
      row[k] = v;
    }
  }
}

extern "C" void kernel_launch(void* const* d_in, const int* in_sizes, int n_in,
                              void* d_out, int out_size, void* d_ws, size_t ws_size,
                              hipStream_t stream) {
  const float* x            = (const float*)d_in[0];
  const int*   cams         = (const int*)d_in[1];
  // d_in[2] = step, d_in[3] = modal : unused by the modal==0 reference path
  const float* att_w        = (const float*)d_in[4];
  const float* att_b        = (const float*)d_in[5];
  const float* running_mean = (const float*)d_in[6];

  float* xout = (float*)d_out;
  float* adj  = xout + XOUT_ELEMS;

  // Scratch consumed strictly BEFORE k_adj lives inside the adj output region
  // (k_adj overwrites every element of it afterwards, stream-ordered).
  float* scores   = adj;            // B floats
  float* partials = adj + B;        // GROUPS*L*C floats (~3 MB)
  // Only the 18-float stats block is read BY k_adj -> keep it in d_ws (72 B).
  float* stats    = (float*)d_ws;

  k_score_copy<<<B, 256, 0, stream>>>(x, cams, att_w, att_b, xout, scores);
  k_stats    <<<1, 256, 0, stream>>>(scores, cams, stats);
  k_partials <<<dim3(2, GROUPS), 256, 0, stream>>>(x, cams, scores, partials);
  k_tail     <<<dim3(2, L),      256, 0, stream>>>(partials, stats, running_mean, xout);
  k_adj      <<<BT, 256, 0, stream>>>(cams, stats, adj);
}